// Round 1
// 787.238 us; speedup vs baseline: 1.0547x; 1.0547x over previous
//
#include <hip/hip_runtime.h>
#include <math.h>

// Choquet tree: B=16 children/node, DEPTH=6, NPAIR=120 (triu k=1), 136 logits/node.
// Per node: m = softmax(theta) ; out = sum(m[:16]*x) + sum(m[16:]*min(x[i],x[j]))
// Implemented unnormalized: (sum w*x + sum w*min) / sum w  with w = exp(theta).
//
// T4 layout: 4 lanes per node. Lane r loads theta quads {r, 4+r, 8+r, ..., 28+r}
// (+ 32+r for r<2), so each wave-level load instruction covers 16 teams x 64
// contiguous bytes — fully line-coalesced (vs 544-B-stride 16-B-granule scatter
// of the thread-per-node version). Pair (i,j) indices are compile-time via a
// constexpr triu table + 4-way switch(r) template specialization; loads are
// hoisted OUTSIDE the divergent switch so coalescing is preserved.

#define BFAC 16
#define NPAIR 120
#define NW 136

struct PairTab { int ii[NPAIR]; int jj[NPAIR]; };
constexpr PairTab make_pairs() {
    PairTab t{};
    int k = 0;
    for (int i = 0; i < BFAC; ++i)
        for (int j = i + 1; j < BFAC; ++j) { t.ii[k] = i; t.jj[k] = j; ++k; }
    return t;
}
constexpr PairTab PT = make_pairs();

// Partial accumulation for lane role R. tq[0] = singleton quad R (theta floats
// 4R..4R+3); tq[s] (s=1..7) = quad 4s+R (pair logits); tq[8] = quad 32+R (R<2).
template <int R>
__device__ __forceinline__ void lane_partial(const float* __restrict__ x,
                                             const float4* __restrict__ tq,
                                             float& acc, float& den) {
    {   // singletons: weights for x[4R .. 4R+3]
        float4 v = tq[0];
        float w0 = __expf(v.x), w1 = __expf(v.y), w2 = __expf(v.z), w3 = __expf(v.w);
        den += (w0 + w1) + (w2 + w3);
        acc += w0 * x[4 * R + 0] + w1 * x[4 * R + 1]
             + w2 * x[4 * R + 2] + w3 * x[4 * R + 3];
    }
#pragma unroll
    for (int s = 1; s <= 7; ++s) {
        float4 v = tq[s];
        const int p0 = 16 * s + 4 * R - 16;   // pair index of v.x
        float w0 = __expf(v.x), w1 = __expf(v.y), w2 = __expf(v.z), w3 = __expf(v.w);
        den += (w0 + w1) + (w2 + w3);
        acc += w0 * fminf(x[PT.ii[p0 + 0]], x[PT.jj[p0 + 0]])
             + w1 * fminf(x[PT.ii[p0 + 1]], x[PT.jj[p0 + 1]])
             + w2 * fminf(x[PT.ii[p0 + 2]], x[PT.jj[p0 + 2]])
             + w3 * fminf(x[PT.ii[p0 + 3]], x[PT.jj[p0 + 3]]);
    }
    if (R < 2) {   // tail quads 32,33 -> pairs 112..119
        float4 v = tq[8];
        const int p0 = 112 + 4 * R;
        float w0 = __expf(v.x), w1 = __expf(v.y), w2 = __expf(v.z), w3 = __expf(v.w);
        den += (w0 + w1) + (w2 + w3);
        acc += w0 * fminf(x[PT.ii[p0 + 0]], x[PT.jj[p0 + 0]])
             + w1 * fminf(x[PT.ii[p0 + 1]], x[PT.jj[p0 + 1]])
             + w2 * fminf(x[PT.ii[p0 + 2]], x[PT.jj[p0 + 2]])
             + w3 * fminf(x[PT.ii[p0 + 3]], x[PT.jj[p0 + 3]]);
    }
}

// One node per 4-lane team. Works for global or LDS `in`/`out`.
__device__ __forceinline__ void choquet_team(const float* in, const float* theta,
                                             float* out, int node, int r) {
    // children: 4 float4s, team-broadcast (all 4 lanes read the same 64 B line)
    const float4* x4 = reinterpret_cast<const float4*>(in) + (size_t)node * 4;
    float x[BFAC];
#pragma unroll
    for (int k = 0; k < 4; ++k) {
        float4 v = x4[k];
        x[4 * k + 0] = v.x; x[4 * k + 1] = v.y;
        x[4 * k + 2] = v.z; x[4 * k + 3] = v.w;
    }
    // theta quads, coalesced across the team (loads OUTSIDE divergent switch)
    const float4* thq = reinterpret_cast<const float4*>(theta) + (size_t)node * 34;
    float4 tq[9];
#pragma unroll
    for (int s = 0; s <= 7; ++s) tq[s] = thq[4 * s + r];  // s=0 -> quad r
    if (r < 2) tq[8] = thq[32 + r];

    float acc = 0.f, den = 0.f;
    switch (r) {   // divergent compute only (register-resident), loads already done
        case 0: lane_partial<0>(x, tq, acc, den); break;
        case 1: lane_partial<1>(x, tq, acc, den); break;
        case 2: lane_partial<2>(x, tq, acc, den); break;
        default: lane_partial<3>(x, tq, acc, den); break;
    }
    // team reduction (xor 1,2 stays within the aligned 4-lane group)
    acc += __shfl_xor(acc, 1); den += __shfl_xor(den, 1);
    acc += __shfl_xor(acc, 2); den += __shfl_xor(den, 2);
    if (r == 0) out[node] = acc / den;
}

// Generic level: 4 threads per node.
__global__ void __launch_bounds__(256)
choquet_level_t4(const float* __restrict__ in, const float* __restrict__ theta,
                 float* __restrict__ out, int n_nodes) {
    int gt = blockIdx.x * 256 + threadIdx.x;
    int node = gt >> 2, r = gt & 3;
    if (node >= n_nodes) return;
    choquet_team(in, theta, out, node, r);
}

// Levels 4 (256 nodes) + 5 (16) + 6 (1) fused in one 1024-thread block via LDS.
__global__ void __launch_bounds__(1024)
choquet_tail_t4(const float* __restrict__ in,
                const float* __restrict__ th4_,
                const float* __restrict__ th5_,
                const float* __restrict__ th6_,
                float* __restrict__ out) {
    __shared__ __align__(16) float l4[256];
    __shared__ __align__(16) float l5[16];
    int t = threadIdx.x;
    choquet_team(in, th4_, l4, t >> 2, t & 3);          // 256 nodes, all 1024 threads
    __syncthreads();
    if (t < 64) choquet_team(l4, th5_, l5, t >> 2, t & 3);   // 16 nodes, wave 0
    __syncthreads();
    if (t < 4) choquet_team(l5, th6_, out, 0, t & 3);        // root
}

extern "C" void kernel_launch(void* const* d_in, const int* in_sizes, int n_in,
                              void* d_out, int out_size, void* d_ws, size_t ws_size,
                              hipStream_t stream) {
    const float* x   = (const float*)d_in[0];
    const float* th1 = (const float*)d_in[1];
    const float* th2 = (const float*)d_in[2];
    const float* th3 = (const float*)d_in[3];
    const float* th4 = (const float*)d_in[4];
    const float* th5 = (const float*)d_in[5];
    const float* th6 = (const float*)d_in[6];
    float* out = (float*)d_out;

    // workspace layout (floats): level1 out 1048576 | level2 out 65536 | level3 out 4096
    float* ws0 = (float*)d_ws;
    float* ws1 = ws0 + 1048576;
    float* ws2 = ws1 + 65536;

    // level 1: 16^5 = 1048576 nodes -> 4 lanes/node -> 16384 blocks of 256
    choquet_level_t4<<<16384, 256, 0, stream>>>(x, th1, ws0, 1048576);
    // level 2: 65536 nodes
    choquet_level_t4<<<1024, 256, 0, stream>>>(ws0, th2, ws1, 65536);
    // level 3: 4096 nodes
    choquet_level_t4<<<64, 256, 0, stream>>>(ws1, th3, ws2, 4096);
    // levels 4..6 fused
    choquet_tail_t4<<<1, 1024, 0, stream>>>(ws2, th4, th5, th6, out);
}